// Round 5
// baseline (137.374 us; speedup 1.0000x reference)
//
#include <hip/hip_runtime.h>

// ---------------------------------------------------------------------------
// Fused GAT module, fp16 MFMA (16x16x32). R5: obs staged as fp16 into LDS with
// row stride 88 (176B, 16B-aligned slices): B-frags load as 6x ds_read_b128,
// bit-cast straight into MFMA operands. Bias-1 column lives at col 83, zeros
// at 84..87. 128-thr blocks = 2 independent waves, each self-stages its own
// LDS half -> no barrier. b1 folded into W1. rcp instead of exact div.
//
// Layout facts used (HW-verified per guide):
//   A-frag: lane l holds A[row = l&15][k = slot(l>>4, i)]
//   B-frag: lane l holds B[k = slot(l>>4, i)][col = l&15]
//   D:      lane l, reg r holds D[4*(l>>4)+r][l&15]
// slot() identical for A and B, so any consistent per-(group,i) k-map works.
// ---------------------------------------------------------------------------

typedef _Float16 half8 __attribute__((ext_vector_type(8)));
typedef _Float16 half4 __attribute__((ext_vector_type(4)));
typedef __fp16 fp16x2 __attribute__((ext_vector_type(2)));
typedef __fp16 fp16x8 __attribute__((ext_vector_type(8)));
typedef float f32x4 __attribute__((ext_vector_type(4)));

#define MFMA16(a, b, c) __builtin_amdgcn_mfma_f32_16x16x32_f16((a), (b), (c), 0, 0, 0)

// workspace byte offsets (all 16B aligned)
#define WS_W1F   0        // 8*3*64*8 half  = 24576 B
#define WS_W2F   24576    // 4*4*64*8 half  = 16384 B
#define WS_WVF   40960    // 4*2*64*8 half  =  8192 B
#define WS_WAFN  49152    // 64*16 f32      =  4096 B
#define WS_WASF  53248    // 64*16 f32      =  4096 B
#define WS_WOPF  57344    // 64*16 f32      =  4096 B
#define WS_ES    61440    // 16384 f32      = 65536 B

#define ROWP 88           // padded row length in fp16 (176 B, 16B-aligned)

__device__ __forceinline__ half8 pack8(float a0, float a1, float a2, float a3,
                                       float a4, float a5, float a6, float a7) {
    fp16x2 p0 = __builtin_amdgcn_cvt_pkrtz(a0, a1);
    fp16x2 p1 = __builtin_amdgcn_cvt_pkrtz(a2, a3);
    fp16x2 p2 = __builtin_amdgcn_cvt_pkrtz(a4, a5);
    fp16x2 p3 = __builtin_amdgcn_cvt_pkrtz(a6, a7);
    fp16x8 h;
    h[0] = p0[0]; h[1] = p0[1]; h[2] = p1[0]; h[3] = p1[1];
    h[4] = p2[0]; h[5] = p2[1]; h[6] = p3[0]; h[7] = p3[1];
    return __builtin_bit_cast(half8, h);
}

// ---------------------------------------------------------------------------
// Prep: build frag-ordered fp16 weights. 27648 threads exactly.
// ---------------------------------------------------------------------------
__global__ void prep_kernel(const float* __restrict__ W1, const float* __restrict__ b1,
                            const float* __restrict__ W2, const float* __restrict__ Wv,
                            const float* __restrict__ Wa, const float* __restrict__ Wo,
                            char* __restrict__ ws) {
    int t = blockIdx.x * 256 + threadIdx.x;
    _Float16* W1f = (_Float16*)(ws + WS_W1F);
    _Float16* W2f = (_Float16*)(ws + WS_W2F);
    _Float16* Wvf = (_Float16*)(ws + WS_WVF);
    float* Wafn = (float*)(ws + WS_WAFN);
    float* Wasf = (float*)(ws + WS_WASF);
    float* Wopf = (float*)(ws + WS_WOPF);

    if (t < 12288) {
        // W1f[hm][kt][lane][i] = W1^T[16hm+m][32kt+8g+i]; k==83 carries b1
        int i = t & 7, lane = (t >> 3) & 63, rest = t >> 9;
        int kt = rest % 3, hm = rest / 3;
        int g = lane >> 4, m = lane & 15;
        int k = 32 * kt + 8 * g + i, h = 16 * hm + m;
        float v = (k < 83) ? W1[k * 128 + h] : (k == 83 ? b1[h] : 0.f);
        W1f[t] = (_Float16)v;
    } else if (t < 20480) {
        // W2f[om][kt][lane][i] = W2[h(kt,g,i)][16om+m], h matches acc1 layout
        int u = t - 12288;
        int i = u & 7, lane = (u >> 3) & 63, rest = u >> 9;
        int kt = rest & 3, om = rest >> 2;
        int g = lane >> 4, m = lane & 15;
        int h = 16 * (2 * kt + (i >> 2)) + 4 * g + (i & 3);
        W2f[u] = (_Float16)W2[h * 64 + 16 * om + m];
    } else if (t < 24576) {
        // Wvf[vm][kt][lane][i] = Wv[o(kt,g,i)][16vm+m]
        int u = t - 20480;
        int i = u & 7, lane = (u >> 3) & 63, rest = u >> 9;
        int kt = rest & 1, vm = rest >> 1;
        int g = lane >> 4, m = lane & 15;
        int o = 16 * (2 * kt + (i >> 2)) + 4 * g + (i & 3);
        Wvf[u] = (_Float16)Wv[o * 64 + 16 * vm + m];
    } else if (t < 25600) {
        int u = t - 24576; int lane = u >> 4, idx = u & 15;
        int g = lane >> 4;
        int o = 16 * (idx >> 2) + 4 * g + (idx & 3);
        Wafn[u] = Wa[64 + o];
    } else if (t < 26624) {
        int u = t - 25600; int lane = u >> 4, idx = u & 15;
        int g = lane >> 4;
        int o = 16 * (idx >> 2) + 4 * g + (idx & 3);
        Wasf[u] = Wa[o];
    } else if (t < 27648) {
        int u = t - 26624; int lane = u >> 4, idx = u & 15;
        int g = lane >> 4, m = lane & 15;
        int vo = 16 * (idx >> 2) + 4 * g + (idx & 3);
        Wopf[u] = Wo[vo * 16 + m];
    }
}

// ---------------------------------------------------------------------------
// Stage 32 rows x 83 f32 (contiguous) -> fp16 LDS rows padded to 88.
// Source reads: 11 aligned dwordx4 per lane. Dest: e + 5*row scatter (b16),
// bank-uniform. Col 83 = bias 1.0, cols 84..87 = 0.
// ---------------------------------------------------------------------------
__device__ __forceinline__ void stage_pad88(const float* __restrict__ src,
                                            _Float16* xs, int lane) {
    const f32x4* s4 = (const f32x4*)src;
#pragma unroll
    for (int t = 0; t < 11; ++t) {
        int u = t * 64 + lane;
        if (t < 10 || u < 664) {
            f32x4 v = s4[u];
            int e0 = 4 * u;
            int row = (int)(((unsigned)e0 * 101068u) >> 23);   // e0/83 exact for e0<2656
            int bnd = row * 83 + 83;
            fp16x2 lo = __builtin_amdgcn_cvt_pkrtz(v[0], v[1]);
            fp16x2 hi = __builtin_amdgcn_cvt_pkrtz(v[2], v[3]);
            __fp16 f[4] = {lo[0], lo[1], hi[0], hi[1]};
#pragma unroll
            for (int j = 0; j < 4; ++j) {
                int e = e0 + j;
                int r = row + (e >= bnd ? 1 : 0);
                xs[e + 5 * r] = (_Float16)f[j];
            }
        }
    }
    if (lane < 32) {
        int rb = lane * ROWP;
        xs[rb + 83] = (_Float16)1.f;                     // bias-1 column
        *(half4*)(xs + rb + 84) = (half4){0, 0, 0, 0};   // zero pad (8B aligned)
    }
}

// ---------------------------------------------------------------------------
// Encode 32 padded LDS rows -> I[om][rn][r] in registers.
// Lane (g,m) holds I[row = 16rn + m][o = 16om + 4g + r].
// ---------------------------------------------------------------------------
__device__ __forceinline__ void encode32p(const _Float16* xs,
                                          const char* __restrict__ ws,
                                          const float* __restrict__ b2,
                                          int lane, float I[4][2][4]) {
    const half8* W1f = (const half8*)(ws + WS_W1F);
    const half8* W2f = (const half8*)(ws + WS_W2F);
    int g = lane >> 4, m = lane & 15;
    const f32x4 zz = {0.f, 0.f, 0.f, 0.f};
    const half8 hz = {0, 0, 0, 0, 0, 0, 0, 0};

    // X^T B-frags: 16B-aligned ds_read_b128, data already in k-order fp16.
    half8 xf[2][3];
#pragma unroll
    for (int rn = 0; rn < 2; ++rn) {
        const _Float16* rp = xs + (16 * rn + m) * ROWP + 8 * g;
#pragma unroll
        for (int kt = 0; kt < 3; ++kt) {
            if (kt == 2 && g == 3) xf[rn][kt] = hz;      // k=88..95: zero
            else xf[rn][kt] = *(const half8*)(rp + 32 * kt);
        }
    }

    // Layer 1: H^T = W1^T @ X^T (b1 folded in); lane holds H[16rn+m][16hm+4g+r]
    f32x4 acc1[8][2];
#pragma unroll
    for (int hm = 0; hm < 8; ++hm) { acc1[hm][0] = zz; acc1[hm][1] = zz; }
#pragma unroll
    for (int hm = 0; hm < 8; ++hm) {
        half8 w0 = W1f[(hm * 3 + 0) * 64 + lane];
        half8 w1 = W1f[(hm * 3 + 1) * 64 + lane];
        half8 w2 = W1f[(hm * 3 + 2) * 64 + lane];
#pragma unroll
        for (int rn = 0; rn < 2; ++rn) {
            acc1[hm][rn] = MFMA16(w0, xf[rn][0], acc1[hm][rn]);
            acc1[hm][rn] = MFMA16(w1, xf[rn][1], acc1[hm][rn]);
            acc1[hm][rn] = MFMA16(w2, xf[rn][2], acc1[hm][rn]);
        }
    }

    // relu + repack acc1 directly into layer-2 B-frags (W2f layout matches)
    half8 hf[4][2];
#pragma unroll
    for (int kt = 0; kt < 4; ++kt)
#pragma unroll
        for (int rn = 0; rn < 2; ++rn) {
            int h0 = 2 * kt, h1 = 2 * kt + 1;
            hf[kt][rn] = pack8(
                fmaxf(acc1[h0][rn][0], 0.f), fmaxf(acc1[h0][rn][1], 0.f),
                fmaxf(acc1[h0][rn][2], 0.f), fmaxf(acc1[h0][rn][3], 0.f),
                fmaxf(acc1[h1][rn][0], 0.f), fmaxf(acc1[h1][rn][1], 0.f),
                fmaxf(acc1[h1][rn][2], 0.f), fmaxf(acc1[h1][rn][3], 0.f));
        }

    // Layer 2: I^T = W2^T @ H^T
    f32x4 acc2[4][2];
#pragma unroll
    for (int om = 0; om < 4; ++om) { acc2[om][0] = zz; acc2[om][1] = zz; }
#pragma unroll
    for (int om = 0; om < 4; ++om) {
        half8 w0 = W2f[(om * 4 + 0) * 64 + lane];
        half8 w1 = W2f[(om * 4 + 1) * 64 + lane];
        half8 w2 = W2f[(om * 4 + 2) * 64 + lane];
        half8 w3 = W2f[(om * 4 + 3) * 64 + lane];
#pragma unroll
        for (int rn = 0; rn < 2; ++rn) {
            acc2[om][rn] = MFMA16(w0, hf[0][rn], acc2[om][rn]);
            acc2[om][rn] = MFMA16(w1, hf[1][rn], acc2[om][rn]);
            acc2[om][rn] = MFMA16(w2, hf[2][rn], acc2[om][rn]);
            acc2[om][rn] = MFMA16(w3, hf[3][rn], acc2[om][rn]);
        }
    }

    // bias + tanh (rcp: ~1 ulp, negligible vs fp16 noise)
#pragma unroll
    for (int om = 0; om < 4; ++om) {
        float b2v[4];
#pragma unroll
        for (int r = 0; r < 4; ++r) b2v[r] = b2[16 * om + 4 * g + r];
#pragma unroll
        for (int rn = 0; rn < 2; ++rn)
#pragma unroll
            for (int r = 0; r < 4; ++r) {
                float y = acc2[om][rn][r] + b2v[r];
                float e = __expf(2.f * y);
                I[om][rn][r] = fmaf(-2.f, __builtin_amdgcn_rcpf(e + 1.f), 1.f);
            }
    }
}

// ---------------------------------------------------------------------------
// Self kernel: es[b] = dot(encode(self_obs[b]), Wa_self). 2 waves/block,
// each wave owns 32 rows + its own LDS half. No barrier.
// ---------------------------------------------------------------------------
__global__ void __launch_bounds__(128, 7)
self_kernel(const float* __restrict__ sobs,
            const float* __restrict__ b2,
            char* __restrict__ ws) {
    __shared__ _Float16 xs[2][32 * ROWP];
    int tid = threadIdx.x, w = tid >> 6, lane = tid & 63;
    int r0 = (blockIdx.x * 2 + w) * 32;

    stage_pad88(sobs + (size_t)r0 * 83, xs[w], lane);

    float I[4][2][4];
    encode32p(xs[w], ws, b2, lane, I);

    const float* Wasf = (const float*)(ws + WS_WASF);
    float* es = (float*)(ws + WS_ES);

    float was[16];
#pragma unroll
    for (int idx = 0; idx < 16; ++idx) was[idx] = Wasf[lane * 16 + idx];

    float d0 = 0.f, d1 = 0.f;
#pragma unroll
    for (int om = 0; om < 4; ++om)
#pragma unroll
        for (int r = 0; r < 4; ++r) {
            d0 = fmaf(I[om][0][r], was[om * 4 + r], d0);
            d1 = fmaf(I[om][1][r], was[om * 4 + r], d1);
        }
    d0 += __shfl_xor(d0, 16); d0 += __shfl_xor(d0, 32);
    d1 += __shfl_xor(d1, 16); d1 += __shfl_xor(d1, 32);

    if (lane < 16) {
        es[r0 + lane] = d0;
        es[r0 + 16 + lane] = d1;
    }
}

// ---------------------------------------------------------------------------
// Main kernel: one batch item per wave, 2 waves/block, no barrier.
// ---------------------------------------------------------------------------
__global__ void __launch_bounds__(128, 7)
main_kernel(const float* __restrict__ nbr,
            const float* __restrict__ edgew,
            const float* __restrict__ b2,
            const float* __restrict__ ba,
            const float* __restrict__ bv,
            const float* __restrict__ bo,
            const char* __restrict__ ws,
            float* __restrict__ out) {
    __shared__ _Float16 xs[2][32 * ROWP];
    int tid = threadIdx.x, w = tid >> 6, lane = tid & 63;
    int b = blockIdx.x * 2 + w;
    int g = lane >> 4, m = lane & 15;
    const f32x4 zz = {0.f, 0.f, 0.f, 0.f};

    const float* es = (const float*)(ws + WS_ES);
    float esb = es[b];              // issued early
    float bav = ba[0];
    float ew0 = edgew[b * 32 + m];
    float ew1 = edgew[b * 32 + 16 + m];

    stage_pad88(nbr + (size_t)b * 2656, xs[w], lane);

    float I[4][2][4];
    encode32p(xs[w], ws, b2, lane, I);

    const float* Wafn = (const float*)(ws + WS_WAFN);
    const float* Wopf = (const float*)(ws + WS_WOPF);
    const half8* Wvf  = (const half8*)(ws + WS_WVF);

    // attention logits: en[row] = dot(I[row], Wa_nbr)
    float wan[16];
#pragma unroll
    for (int idx = 0; idx < 16; ++idx) wan[idx] = Wafn[lane * 16 + idx];

    float en0 = 0.f, en1 = 0.f;
#pragma unroll
    for (int om = 0; om < 4; ++om)
#pragma unroll
        for (int r = 0; r < 4; ++r) {
            en0 = fmaf(I[om][0][r], wan[om * 4 + r], en0);
            en1 = fmaf(I[om][1][r], wan[om * 4 + r], en1);
        }
    en0 += __shfl_xor(en0, 16); en0 += __shfl_xor(en0, 32);
    en1 += __shfl_xor(en1, 16); en1 += __shfl_xor(en1, 32);

    float e0 = esb + en0 + bav; e0 = (e0 > 0.f) ? e0 : 0.2f * e0; e0 *= ew0;
    float e1 = esb + en1 + bav; e1 = (e1 > 0.f) ? e1 : 0.2f * e1; e1 *= ew1;

    // softmax over 32 neighbors; |e| bounded (~7) -> exp fp32-safe w/o max-sub
    float p0 = __expf(e0), p1 = __expf(e1);
    float s = p0 + p1;
#pragma unroll
    for (int msk = 1; msk <= 8; msk <<= 1) s += __shfl_xor(s, msk);
    float inv = __builtin_amdgcn_rcpf(s);
    float a0 = p0 * inv, a1 = p1 * inv;

    // values: V^T = Wv^T @ I^T, B-frag straight from I registers
    half8 vf[2][2];
#pragma unroll
    for (int kt = 0; kt < 2; ++kt)
#pragma unroll
        for (int rn = 0; rn < 2; ++rn)
            vf[kt][rn] = pack8(I[2 * kt][rn][0], I[2 * kt][rn][1],
                               I[2 * kt][rn][2], I[2 * kt][rn][3],
                               I[2 * kt + 1][rn][0], I[2 * kt + 1][rn][1],
                               I[2 * kt + 1][rn][2], I[2 * kt + 1][rn][3]);

    f32x4 acc3[4][2];
#pragma unroll
    for (int vm = 0; vm < 4; ++vm) { acc3[vm][0] = zz; acc3[vm][1] = zz; }
#pragma unroll
    for (int vm = 0; vm < 4; ++vm) {
        half8 w0 = Wvf[(vm * 2 + 0) * 64 + lane];
        half8 w1 = Wvf[(vm * 2 + 1) * 64 + lane];
#pragma unroll
        for (int rn = 0; rn < 2; ++rn) {
            acc3[vm][rn] = MFMA16(w0, vf[0][rn], acc3[vm][rn]);
            acc3[vm][rn] = MFMA16(w1, vf[1][rn], acc3[vm][rn]);
        }
    }

    // agg[vo] = sum_nbr alpha * V[nbr][vo] + bv[vo]
    float agg[4][4];
#pragma unroll
    for (int vm = 0; vm < 4; ++vm)
#pragma unroll
        for (int r = 0; r < 4; ++r) {
            float t = a0 * acc3[vm][0][r] + a1 * acc3[vm][1][r];
#pragma unroll
            for (int msk = 1; msk <= 8; msk <<= 1) t += __shfl_xor(t, msk);
            agg[vm][r] = t + bv[16 * vm + 4 * g + r];
        }

    // out[b][j]: lane (g,m) computes j = m over its vo subset, then g-reduce
    float wor[16];
#pragma unroll
    for (int idx = 0; idx < 16; ++idx) wor[idx] = Wopf[lane * 16 + idx];
    float val = 0.f;
#pragma unroll
    for (int vm = 0; vm < 4; ++vm)
#pragma unroll
        for (int r = 0; r < 4; ++r) val = fmaf(agg[vm][r], wor[vm * 4 + r], val);
    val += __shfl_xor(val, 16);
    val += __shfl_xor(val, 32);

    if (lane < 16) out[(size_t)b * 16 + lane] = val + bo[lane];
}

// ---------------------------------------------------------------------------
extern "C" void kernel_launch(void* const* d_in, const int* in_sizes, int n_in,
                              void* d_out, int out_size, void* d_ws, size_t ws_size,
                              hipStream_t stream) {
    const float* self_obs = (const float*)d_in[0];
    const float* nbr      = (const float*)d_in[1];
    const float* ew       = (const float*)d_in[2];
    const float* W1       = (const float*)d_in[3];
    const float* b1       = (const float*)d_in[4];
    const float* W2       = (const float*)d_in[5];
    const float* b2       = (const float*)d_in[6];
    const float* Wa       = (const float*)d_in[7];
    const float* ba       = (const float*)d_in[8];
    const float* Wv       = (const float*)d_in[9];
    const float* bv       = (const float*)d_in[10];
    const float* Wo       = (const float*)d_in[11];
    const float* bo       = (const float*)d_in[12];
    char* ws = (char*)d_ws;
    float* out = (float*)d_out;

    prep_kernel<<<108, 256, 0, stream>>>(W1, b1, W2, Wv, Wa, Wo, ws);
    self_kernel<<<256, 128, 0, stream>>>(self_obs, b2, ws);
    main_kernel<<<8192, 128, 0, stream>>>(nbr, ew, b2, ba, bv, bo, ws, out);
}

// Round 6
// 74.221 us; speedup vs baseline: 1.8509x; 1.8509x over previous
//
#include <hip/hip_runtime.h>

// ---------------------------------------------------------------------------
// Fused GAT module, fp16 MFMA (16x16x32). R6 = R5 with the launch_bounds spill
// fix: (128,7) capped VGPRs at ~73 and spilled the MFMA accumulators to
// scratch (177 MB of scratch writes/dispatch). Now (128,4) -> 128-VGPR cap.
// Structure: obs staged as fp16 into LDS rows padded to 88 (176B, 16B-aligned
// slices) -> B-frags are 6x ds_read_b128 bit-cast to MFMA operands; bias-1
// col at 83, zeros 84..87; 2 independent waves/block, no barrier; b1 folded
// into W1; rcp for divides.
// ---------------------------------------------------------------------------

typedef _Float16 half8 __attribute__((ext_vector_type(8)));
typedef _Float16 half4 __attribute__((ext_vector_type(4)));
typedef __fp16 fp16x2 __attribute__((ext_vector_type(2)));
typedef __fp16 fp16x8 __attribute__((ext_vector_type(8)));
typedef float f32x4 __attribute__((ext_vector_type(4)));

#define MFMA16(a, b, c) __builtin_amdgcn_mfma_f32_16x16x32_f16((a), (b), (c), 0, 0, 0)

// workspace byte offsets (all 16B aligned)
#define WS_W1F   0        // 8*3*64*8 half  = 24576 B
#define WS_W2F   24576    // 4*4*64*8 half  = 16384 B
#define WS_WVF   40960    // 4*2*64*8 half  =  8192 B
#define WS_WAFN  49152    // 64*16 f32      =  4096 B
#define WS_WASF  53248    // 64*16 f32      =  4096 B
#define WS_WOPF  57344    // 64*16 f32      =  4096 B
#define WS_ES    61440    // 16384 f32      = 65536 B

#define ROWP 88           // padded row length in fp16 (176 B, 16B-aligned)

__device__ __forceinline__ half8 pack8(float a0, float a1, float a2, float a3,
                                       float a4, float a5, float a6, float a7) {
    fp16x2 p0 = __builtin_amdgcn_cvt_pkrtz(a0, a1);
    fp16x2 p1 = __builtin_amdgcn_cvt_pkrtz(a2, a3);
    fp16x2 p2 = __builtin_amdgcn_cvt_pkrtz(a4, a5);
    fp16x2 p3 = __builtin_amdgcn_cvt_pkrtz(a6, a7);
    fp16x8 h;
    h[0] = p0[0]; h[1] = p0[1]; h[2] = p1[0]; h[3] = p1[1];
    h[4] = p2[0]; h[5] = p2[1]; h[6] = p3[0]; h[7] = p3[1];
    return __builtin_bit_cast(half8, h);
}

// ---------------------------------------------------------------------------
// Prep: build frag-ordered fp16 weights. 27648 threads exactly.
// ---------------------------------------------------------------------------
__global__ void prep_kernel(const float* __restrict__ W1, const float* __restrict__ b1,
                            const float* __restrict__ W2, const float* __restrict__ Wv,
                            const float* __restrict__ Wa, const float* __restrict__ Wo,
                            char* __restrict__ ws) {
    int t = blockIdx.x * 256 + threadIdx.x;
    _Float16* W1f = (_Float16*)(ws + WS_W1F);
    _Float16* W2f = (_Float16*)(ws + WS_W2F);
    _Float16* Wvf = (_Float16*)(ws + WS_WVF);
    float* Wafn = (float*)(ws + WS_WAFN);
    float* Wasf = (float*)(ws + WS_WASF);
    float* Wopf = (float*)(ws + WS_WOPF);

    if (t < 12288) {
        // W1f[hm][kt][lane][i] = W1^T[16hm+m][32kt+8g+i]; k==83 carries b1
        int i = t & 7, lane = (t >> 3) & 63, rest = t >> 9;
        int kt = rest % 3, hm = rest / 3;
        int g = lane >> 4, m = lane & 15;
        int k = 32 * kt + 8 * g + i, h = 16 * hm + m;
        float v = (k < 83) ? W1[k * 128 + h] : (k == 83 ? b1[h] : 0.f);
        W1f[t] = (_Float16)v;
    } else if (t < 20480) {
        // W2f[om][kt][lane][i] = W2[h(kt,g,i)][16om+m], h matches acc1 layout
        int u = t - 12288;
        int i = u & 7, lane = (u >> 3) & 63, rest = u >> 9;
        int kt = rest & 3, om = rest >> 2;
        int g = lane >> 4, m = lane & 15;
        int h = 16 * (2 * kt + (i >> 2)) + 4 * g + (i & 3);
        W2f[u] = (_Float16)W2[h * 64 + 16 * om + m];
    } else if (t < 24576) {
        // Wvf[vm][kt][lane][i] = Wv[o(kt,g,i)][16vm+m]
        int u = t - 20480;
        int i = u & 7, lane = (u >> 3) & 63, rest = u >> 9;
        int kt = rest & 1, vm = rest >> 1;
        int g = lane >> 4, m = lane & 15;
        int o = 16 * (2 * kt + (i >> 2)) + 4 * g + (i & 3);
        Wvf[u] = (_Float16)Wv[o * 64 + 16 * vm + m];
    } else if (t < 25600) {
        int u = t - 24576; int lane = u >> 4, idx = u & 15;
        int g = lane >> 4;
        int o = 16 * (idx >> 2) + 4 * g + (idx & 3);
        Wafn[u] = Wa[64 + o];
    } else if (t < 26624) {
        int u = t - 25600; int lane = u >> 4, idx = u & 15;
        int g = lane >> 4;
        int o = 16 * (idx >> 2) + 4 * g + (idx & 3);
        Wasf[u] = Wa[o];
    } else if (t < 27648) {
        int u = t - 26624; int lane = u >> 4, idx = u & 15;
        int g = lane >> 4, m = lane & 15;
        int vo = 16 * (idx >> 2) + 4 * g + (idx & 3);
        Wopf[u] = Wo[vo * 16 + m];
    }
}

// ---------------------------------------------------------------------------
// Stage 32 rows x 83 f32 (contiguous) -> fp16 LDS rows padded to 88.
// Source reads: 11 aligned dwordx4 per lane. Dest: e + 5*row scatter (b16).
// Col 83 = bias 1.0, cols 84..87 = 0.
// ---------------------------------------------------------------------------
__device__ __forceinline__ void stage_pad88(const float* __restrict__ src,
                                            _Float16* xs, int lane) {
    const f32x4* s4 = (const f32x4*)src;
#pragma unroll
    for (int t = 0; t < 11; ++t) {
        int u = t * 64 + lane;
        if (t < 10 || u < 664) {
            f32x4 v = s4[u];
            int e0 = 4 * u;
            int row = (int)(((unsigned)e0 * 101068u) >> 23);   // e0/83 exact for e0<2656
            int bnd = row * 83 + 83;
            fp16x2 lo = __builtin_amdgcn_cvt_pkrtz(v[0], v[1]);
            fp16x2 hi = __builtin_amdgcn_cvt_pkrtz(v[2], v[3]);
            __fp16 f0 = lo[0], f1 = lo[1], f2 = hi[0], f3 = hi[1];
            int r0 = row + (e0 + 0 >= bnd ? 1 : 0);
            int r1 = row + (e0 + 1 >= bnd ? 1 : 0);
            int r2 = row + (e0 + 2 >= bnd ? 1 : 0);
            int r3 = row + (e0 + 3 >= bnd ? 1 : 0);
            xs[e0 + 0 + 5 * r0] = (_Float16)f0;
            xs[e0 + 1 + 5 * r1] = (_Float16)f1;
            xs[e0 + 2 + 5 * r2] = (_Float16)f2;
            xs[e0 + 3 + 5 * r3] = (_Float16)f3;
        }
    }
    if (lane < 32) {
        int rb = lane * ROWP;
        xs[rb + 83] = (_Float16)1.f;                     // bias-1 column
        *(half4*)(xs + rb + 84) = (half4){0, 0, 0, 0};   // zero pad (8B aligned)
    }
}

// ---------------------------------------------------------------------------
// Encode 32 padded LDS rows -> I[om][rn][r] in registers.
// Lane (g,m) holds I[row = 16rn + m][o = 16om + 4g + r].
// ---------------------------------------------------------------------------
__device__ __forceinline__ void encode32p(const _Float16* xs,
                                          const char* __restrict__ ws,
                                          const float* __restrict__ b2,
                                          int lane, float I[4][2][4]) {
    const half8* W1f = (const half8*)(ws + WS_W1F);
    const half8* W2f = (const half8*)(ws + WS_W2F);
    int g = lane >> 4, m = lane & 15;
    const f32x4 zz = {0.f, 0.f, 0.f, 0.f};
    const half8 hz = {0, 0, 0, 0, 0, 0, 0, 0};

    // X^T B-frags: 16B-aligned ds_read_b128, data already in k-order fp16.
    half8 xf[2][3];
#pragma unroll
    for (int rn = 0; rn < 2; ++rn) {
        const _Float16* rp = xs + (16 * rn + m) * ROWP + 8 * g;
#pragma unroll
        for (int kt = 0; kt < 3; ++kt) {
            if (kt == 2 && g == 3) xf[rn][kt] = hz;      // k=88..95: zero
            else xf[rn][kt] = *(const half8*)(rp + 32 * kt);
        }
    }

    // Layer 1: H^T = W1^T @ X^T (b1 folded in); lane holds H[16rn+m][16hm+4g+r]
    f32x4 acc1[8][2];
#pragma unroll
    for (int hm = 0; hm < 8; ++hm) { acc1[hm][0] = zz; acc1[hm][1] = zz; }
#pragma unroll
    for (int hm = 0; hm < 8; ++hm) {
        half8 w0 = W1f[(hm * 3 + 0) * 64 + lane];
        half8 w1 = W1f[(hm * 3 + 1) * 64 + lane];
        half8 w2 = W1f[(hm * 3 + 2) * 64 + lane];
#pragma unroll
        for (int rn = 0; rn < 2; ++rn) {
            acc1[hm][rn] = MFMA16(w0, xf[rn][0], acc1[hm][rn]);
            acc1[hm][rn] = MFMA16(w1, xf[rn][1], acc1[hm][rn]);
            acc1[hm][rn] = MFMA16(w2, xf[rn][2], acc1[hm][rn]);
        }
    }

    // relu + repack acc1 directly into layer-2 B-frags (W2f layout matches)
    half8 hf[4][2];
#pragma unroll
    for (int kt = 0; kt < 4; ++kt)
#pragma unroll
        for (int rn = 0; rn < 2; ++rn) {
            int h0 = 2 * kt, h1 = 2 * kt + 1;
            hf[kt][rn] = pack8(
                fmaxf(acc1[h0][rn][0], 0.f), fmaxf(acc1[h0][rn][1], 0.f),
                fmaxf(acc1[h0][rn][2], 0.f), fmaxf(acc1[h0][rn][3], 0.f),
                fmaxf(acc1[h1][rn][0], 0.f), fmaxf(acc1[h1][rn][1], 0.f),
                fmaxf(acc1[h1][rn][2], 0.f), fmaxf(acc1[h1][rn][3], 0.f));
        }

    // Layer 2: I^T = W2^T @ H^T
    f32x4 acc2[4][2];
#pragma unroll
    for (int om = 0; om < 4; ++om) { acc2[om][0] = zz; acc2[om][1] = zz; }
#pragma unroll
    for (int om = 0; om < 4; ++om) {
        half8 w0 = W2f[(om * 4 + 0) * 64 + lane];
        half8 w1 = W2f[(om * 4 + 1) * 64 + lane];
        half8 w2 = W2f[(om * 4 + 2) * 64 + lane];
        half8 w3 = W2f[(om * 4 + 3) * 64 + lane];
#pragma unroll
        for (int rn = 0; rn < 2; ++rn) {
            acc2[om][rn] = MFMA16(w0, hf[0][rn], acc2[om][rn]);
            acc2[om][rn] = MFMA16(w1, hf[1][rn], acc2[om][rn]);
            acc2[om][rn] = MFMA16(w2, hf[2][rn], acc2[om][rn]);
            acc2[om][rn] = MFMA16(w3, hf[3][rn], acc2[om][rn]);
        }
    }

    // bias + tanh (rcp: ~1 ulp, negligible vs fp16 noise)
#pragma unroll
    for (int om = 0; om < 4; ++om) {
        float b2v[4];
#pragma unroll
        for (int r = 0; r < 4; ++r) b2v[r] = b2[16 * om + 4 * g + r];
#pragma unroll
        for (int rn = 0; rn < 2; ++rn)
#pragma unroll
            for (int r = 0; r < 4; ++r) {
                float y = acc2[om][rn][r] + b2v[r];
                float e = __expf(2.f * y);
                I[om][rn][r] = fmaf(-2.f, __builtin_amdgcn_rcpf(e + 1.f), 1.f);
            }
    }
}

// ---------------------------------------------------------------------------
// Self kernel: es[b] = dot(encode(self_obs[b]), Wa_self). 2 waves/block,
// each wave owns 32 rows + its own LDS half. No barrier.
// ---------------------------------------------------------------------------
__global__ void __launch_bounds__(128, 4)
self_kernel(const float* __restrict__ sobs,
            const float* __restrict__ b2,
            char* __restrict__ ws) {
    __shared__ _Float16 xs[2][32 * ROWP];
    int tid = threadIdx.x, w = tid >> 6, lane = tid & 63;
    int r0 = (blockIdx.x * 2 + w) * 32;

    stage_pad88(sobs + (size_t)r0 * 83, xs[w], lane);

    float I[4][2][4];
    encode32p(xs[w], ws, b2, lane, I);

    const float* Wasf = (const float*)(ws + WS_WASF);
    float* es = (float*)(ws + WS_ES);

    float was[16];
#pragma unroll
    for (int idx = 0; idx < 16; ++idx) was[idx] = Wasf[lane * 16 + idx];

    float d0 = 0.f, d1 = 0.f;
#pragma unroll
    for (int om = 0; om < 4; ++om)
#pragma unroll
        for (int r = 0; r < 4; ++r) {
            d0 = fmaf(I[om][0][r], was[om * 4 + r], d0);
            d1 = fmaf(I[om][1][r], was[om * 4 + r], d1);
        }
    d0 += __shfl_xor(d0, 16); d0 += __shfl_xor(d0, 32);
    d1 += __shfl_xor(d1, 16); d1 += __shfl_xor(d1, 32);

    if (lane < 16) {
        es[r0 + lane] = d0;
        es[r0 + 16 + lane] = d1;
    }
}

// ---------------------------------------------------------------------------
// Main kernel: one batch item per wave, 2 waves/block, no barrier.
// ---------------------------------------------------------------------------
__global__ void __launch_bounds__(128, 4)
main_kernel(const float* __restrict__ nbr,
            const float* __restrict__ edgew,
            const float* __restrict__ b2,
            const float* __restrict__ ba,
            const float* __restrict__ bv,
            const float* __restrict__ bo,
            const char* __restrict__ ws,
            float* __restrict__ out) {
    __shared__ _Float16 xs[2][32 * ROWP];
    int tid = threadIdx.x, w = tid >> 6, lane = tid & 63;
    int b = blockIdx.x * 2 + w;
    int g = lane >> 4, m = lane & 15;
    const f32x4 zz = {0.f, 0.f, 0.f, 0.f};

    const float* es = (const float*)(ws + WS_ES);
    float esb = es[b];              // issued early
    float bav = ba[0];
    float ew0 = edgew[b * 32 + m];
    float ew1 = edgew[b * 32 + 16 + m];

    stage_pad88(nbr + (size_t)b * 2656, xs[w], lane);

    float I[4][2][4];
    encode32p(xs[w], ws, b2, lane, I);

    const float* Wafn = (const float*)(ws + WS_WAFN);
    const float* Wopf = (const float*)(ws + WS_WOPF);
    const half8* Wvf  = (const half8*)(ws + WS_WVF);

    // attention logits: en[row] = dot(I[row], Wa_nbr)
    float wan[16];
#pragma unroll
    for (int idx = 0; idx < 16; ++idx) wan[idx] = Wafn[lane * 16 + idx];

    float en0 = 0.f, en1 = 0.f;
#pragma unroll
    for (int om = 0; om < 4; ++om)
#pragma unroll
        for (int r = 0; r < 4; ++r) {
            en0 = fmaf(I[om][0][r], wan[om * 4 + r], en0);
            en1 = fmaf(I[om][1][r], wan[om * 4 + r], en1);
        }
    en0 += __shfl_xor(en0, 16); en0 += __shfl_xor(en0, 32);
    en1 += __shfl_xor(en1, 16); en1 += __shfl_xor(en1, 32);

    float e0 = esb + en0 + bav; e0 = (e0 > 0.f) ? e0 : 0.2f * e0; e0 *= ew0;
    float e1 = esb + en1 + bav; e1 = (e1 > 0.f) ? e1 : 0.2f * e1; e1 *= ew1;

    // softmax over 32 neighbors; |e| bounded (~7) -> exp fp32-safe w/o max-sub
    float p0 = __expf(e0), p1 = __expf(e1);
    float s = p0 + p1;
#pragma unroll
    for (int msk = 1; msk <= 8; msk <<= 1) s += __shfl_xor(s, msk);
    float inv = __builtin_amdgcn_rcpf(s);
    float a0 = p0 * inv, a1 = p1 * inv;

    // values: V^T = Wv^T @ I^T, B-frag straight from I registers
    half8 vf[2][2];
#pragma unroll
    for (int kt = 0; kt < 2; ++kt)
#pragma unroll
        for (int rn = 0; rn < 2; ++rn)
            vf[kt][rn] = pack8(I[2 * kt][rn][0], I[2 * kt][rn][1],
                               I[2 * kt][rn][2], I[2 * kt][rn][3],
                               I[2 * kt + 1][rn][0], I[2 * kt + 1][rn][1],
                               I[2 * kt + 1][rn][2], I[2 * kt + 1][rn][3]);

    f32x4 acc3[4][2];
#pragma unroll
    for (int vm = 0; vm < 4; ++vm) { acc3[vm][0] = zz; acc3[vm][1] = zz; }
#pragma unroll
    for (int vm = 0; vm < 4; ++vm) {
        half8 w0 = Wvf[(vm * 2 + 0) * 64 + lane];
        half8 w1 = Wvf[(vm * 2 + 1) * 64 + lane];
#pragma unroll
        for (int rn = 0; rn < 2; ++rn) {
            acc3[vm][rn] = MFMA16(w0, vf[0][rn], acc3[vm][rn]);
            acc3[vm][rn] = MFMA16(w1, vf[1][rn], acc3[vm][rn]);
        }
    }

    // agg[vo] = sum_nbr alpha * V[nbr][vo] + bv[vo]
    float agg[4][4];
#pragma unroll
    for (int vm = 0; vm < 4; ++vm)
#pragma unroll
        for (int r = 0; r < 4; ++r) {
            float t = a0 * acc3[vm][0][r] + a1 * acc3[vm][1][r];
#pragma unroll
            for (int msk = 1; msk <= 8; msk <<= 1) t += __shfl_xor(t, msk);
            agg[vm][r] = t + bv[16 * vm + 4 * g + r];
        }

    // out[b][j]: lane (g,m) computes j = m over its vo subset, then g-reduce
    float wor[16];
#pragma unroll
    for (int idx = 0; idx < 16; ++idx) wor[idx] = Wopf[lane * 16 + idx];
    float val = 0.f;
#pragma unroll
    for (int vm = 0; vm < 4; ++vm)
#pragma unroll
        for (int r = 0; r < 4; ++r) val = fmaf(agg[vm][r], wor[vm * 4 + r], val);
    val += __shfl_xor(val, 16);
    val += __shfl_xor(val, 32);

    if (lane < 16) out[(size_t)b * 16 + lane] = val + bo[lane];
}

// ---------------------------------------------------------------------------
extern "C" void kernel_launch(void* const* d_in, const int* in_sizes, int n_in,
                              void* d_out, int out_size, void* d_ws, size_t ws_size,
                              hipStream_t stream) {
    const float* self_obs = (const float*)d_in[0];
    const float* nbr      = (const float*)d_in[1];
    const float* ew       = (const float*)d_in[2];
    const float* W1       = (const float*)d_in[3];
    const float* b1       = (const float*)d_in[4];
    const float* W2       = (const float*)d_in[5];
    const float* b2       = (const float*)d_in[6];
    const float* Wa       = (const float*)d_in[7];
    const float* ba       = (const float*)d_in[8];
    const float* Wv       = (const float*)d_in[9];
    const float* bv       = (const float*)d_in[10];
    const float* Wo       = (const float*)d_in[11];
    const float* bo       = (const float*)d_in[12];
    char* ws = (char*)d_ws;
    float* out = (float*)d_out;

    prep_kernel<<<108, 256, 0, stream>>>(W1, b1, W2, Wv, Wa, Wo, ws);
    self_kernel<<<256, 128, 0, stream>>>(self_obs, b2, ws);
    main_kernel<<<8192, 128, 0, stream>>>(nbr, ew, b2, ba, bv, bo, ws, out);
}

// Round 7
// 62.297 us; speedup vs baseline: 2.2052x; 1.1914x over previous
//
#include <hip/hip_runtime.h>

// ---------------------------------------------------------------------------
// Fused GAT module, fp16 MFMA (16x16x32). R7: weights BLOCK-SHARED IN LDS.
// Diagnosis: R3-R6 all ~100-116us with VALUBusy~29% regardless of obs path;
// the invariant was 48KB/wave of frag-ordered weights streamed from global
// (L1-thrashed -> ~250cy L2 latency chain). Now each 512-thr block stages the
// 48KB frag region into LDS once (linear b128, 1 barrier), waves read weights
// via conflict-free ds_read_b128. Obs goes direct global->reg as align-4
// dwordx4 slices (no LDS obs buffer). Layer-1 uses hm-pair scoped
// accumulators and layer-2 is per-om to cap VGPR pressure.
//
// Layout facts used (HW-verified per guide):
//   A-frag: lane l holds A[row = l&15][k = slot(l>>4, i)]
//   B-frag: lane l holds B[k = slot(l>>4, i)][col = l&15]
//   D:      lane l, reg r holds D[4*(l>>4)+r][l&15]
// slot() identical for A and B, so any consistent per-(group,i) k-map works.
// ---------------------------------------------------------------------------

typedef _Float16 half8 __attribute__((ext_vector_type(8)));
typedef __fp16 fp16x2 __attribute__((ext_vector_type(2)));
typedef __fp16 fp16x8 __attribute__((ext_vector_type(8)));
typedef float f32x4 __attribute__((ext_vector_type(4)));

// packed+aligned(4) wrapper: lets the backend emit dwordx4 at 4B alignment
struct __attribute__((packed, aligned(4))) F4 { f32x4 v; };

__device__ __forceinline__ f32x4 ld4(const float* p) {
    return ((const F4*)p)->v;
}

#define MFMA16(a, b, c) __builtin_amdgcn_mfma_f32_16x16x32_f16((a), (b), (c), 0, 0, 0)

// workspace byte offsets (all 16B aligned)
#define WS_W1F   0        // 8*3*64*8 half  = 24576 B
#define WS_W2F   24576    // 4*4*64*8 half  = 16384 B
#define WS_WVF   40960    // 4*2*64*8 half  =  8192 B
#define WS_WFRAG 49152    // total staged frag bytes
#define WS_WAFN  49152    // 64*16 f32      =  4096 B
#define WS_WASF  53248    // 64*16 f32      =  4096 B
#define WS_WOPF  57344    // 64*16 f32      =  4096 B
#define WS_ES    61440    // 16384 f32      = 65536 B

__device__ __forceinline__ half8 pack8(float a0, float a1, float a2, float a3,
                                       float a4, float a5, float a6, float a7) {
    fp16x2 p0 = __builtin_amdgcn_cvt_pkrtz(a0, a1);
    fp16x2 p1 = __builtin_amdgcn_cvt_pkrtz(a2, a3);
    fp16x2 p2 = __builtin_amdgcn_cvt_pkrtz(a4, a5);
    fp16x2 p3 = __builtin_amdgcn_cvt_pkrtz(a6, a7);
    fp16x8 h;
    h[0] = p0[0]; h[1] = p0[1]; h[2] = p1[0]; h[3] = p1[1];
    h[4] = p2[0]; h[5] = p2[1]; h[6] = p3[0]; h[7] = p3[1];
    return __builtin_bit_cast(half8, h);
}

// ---------------------------------------------------------------------------
// Prep: build frag-ordered fp16 weights. 27648 threads exactly.
// ---------------------------------------------------------------------------
__global__ void prep_kernel(const float* __restrict__ W1, const float* __restrict__ b1,
                            const float* __restrict__ W2, const float* __restrict__ Wv,
                            const float* __restrict__ Wa, const float* __restrict__ Wo,
                            char* __restrict__ ws) {
    int t = blockIdx.x * 256 + threadIdx.x;
    _Float16* W1f = (_Float16*)(ws + WS_W1F);
    _Float16* W2f = (_Float16*)(ws + WS_W2F);
    _Float16* Wvf = (_Float16*)(ws + WS_WVF);
    float* Wafn = (float*)(ws + WS_WAFN);
    float* Wasf = (float*)(ws + WS_WASF);
    float* Wopf = (float*)(ws + WS_WOPF);

    if (t < 12288) {
        // W1f[hm][kt][lane][i] = W1^T[16hm+m][32kt+8g+i]; k==83 carries b1
        int i = t & 7, lane = (t >> 3) & 63, rest = t >> 9;
        int kt = rest % 3, hm = rest / 3;
        int g = lane >> 4, m = lane & 15;
        int k = 32 * kt + 8 * g + i, h = 16 * hm + m;
        float v = (k < 83) ? W1[k * 128 + h] : (k == 83 ? b1[h] : 0.f);
        W1f[t] = (_Float16)v;
    } else if (t < 20480) {
        // W2f[om][kt][lane][i] = W2[h(kt,g,i)][16om+m], h matches acc1 layout
        int u = t - 12288;
        int i = u & 7, lane = (u >> 3) & 63, rest = u >> 9;
        int kt = rest & 3, om = rest >> 2;
        int g = lane >> 4, m = lane & 15;
        int h = 16 * (2 * kt + (i >> 2)) + 4 * g + (i & 3);
        W2f[u] = (_Float16)W2[h * 64 + 16 * om + m];
    } else if (t < 24576) {
        // Wvf[vm][kt][lane][i] = Wv[o(kt,g,i)][16vm+m]
        int u = t - 20480;
        int i = u & 7, lane = (u >> 3) & 63, rest = u >> 9;
        int kt = rest & 1, vm = rest >> 1;
        int g = lane >> 4, m = lane & 15;
        int o = 16 * (2 * kt + (i >> 2)) + 4 * g + (i & 3);
        Wvf[u] = (_Float16)Wv[o * 64 + 16 * vm + m];
    } else if (t < 25600) {
        int u = t - 24576; int lane = u >> 4, idx = u & 15;
        int g = lane >> 4;
        int o = 16 * (idx >> 2) + 4 * g + (idx & 3);
        Wafn[u] = Wa[64 + o];
    } else if (t < 26624) {
        int u = t - 25600; int lane = u >> 4, idx = u & 15;
        int g = lane >> 4;
        int o = 16 * (idx >> 2) + 4 * g + (idx & 3);
        Wasf[u] = Wa[o];
    } else if (t < 27648) {
        int u = t - 26624; int lane = u >> 4, idx = u & 15;
        int g = lane >> 4, m = lane & 15;
        int vo = 16 * (idx >> 2) + 4 * g + (idx & 3);
        Wopf[u] = Wo[vo * 16 + m];
    }
}

// ---------------------------------------------------------------------------
// Stage the 48KB weight-frag region ws[0..49152) into LDS. 512 threads.
// ---------------------------------------------------------------------------
__device__ __forceinline__ void stage_weights(const char* __restrict__ ws,
                                              char* wlds, int tid) {
    const f32x4* s4 = (const f32x4*)ws;
    f32x4* d4 = (f32x4*)wlds;
#pragma unroll
    for (int t = 0; t < 6; ++t) d4[t * 512 + tid] = s4[t * 512 + tid];
    __syncthreads();
}

// ---------------------------------------------------------------------------
// Encode 32 rows (global, contiguous, row stride 83 f32) -> I[om][rn][r].
// Weights from LDS. Lane (g,m) holds I[row = 16rn + m][o = 16om + 4g + r].
// ---------------------------------------------------------------------------
__device__ __forceinline__ void encode32d(const float* __restrict__ src,
                                          const char* wlds,
                                          const float* __restrict__ b2,
                                          int lane, float I[4][2][4]) {
    const half8* W1f = (const half8*)(wlds + WS_W1F);
    const half8* W2f = (const half8*)(wlds + WS_W2F);
    int g = lane >> 4, m = lane & 15;
    const f32x4 zz = {0.f, 0.f, 0.f, 0.f};

    // X^T B-frags straight from global (align-4 dwordx4 slices)
    half8 xf[2][3];
#pragma unroll
    for (int rn = 0; rn < 2; ++rn) {
        const float* rp = src + (16 * rn + m) * 83;
#pragma unroll
        for (int kt = 0; kt < 2; ++kt) {
            f32x4 a = ld4(rp + 32 * kt + 8 * g);
            f32x4 c = ld4(rp + 32 * kt + 8 * g + 4);
            xf[rn][kt] = pack8(a[0], a[1], a[2], a[3], c[0], c[1], c[2], c[3]);
        }
        half8 h;
        if (g < 2) {                          // k = 64+8g .. 71+8g  (<= 79)
            f32x4 a = ld4(rp + 64 + 8 * g);
            f32x4 c = ld4(rp + 68 + 8 * g);
            h = pack8(a[0], a[1], a[2], a[3], c[0], c[1], c[2], c[3]);
        } else if (g == 2) {                  // k = 80,81,82, bias-1, 0...
            h = pack8(rp[80], rp[81], rp[82], 1.f, 0.f, 0.f, 0.f, 0.f);
        } else {                              // k = 88..95: zero pad
            h = pack8(0.f, 0.f, 0.f, 0.f, 0.f, 0.f, 0.f, 0.f);
        }
        xf[rn][2] = h;
    }

    // Layer 1 per hm-pair with scoped accumulators; relu+pack immediately.
    half8 hf[4][2];
#pragma unroll
    for (int t = 0; t < 4; ++t) {
        int h0 = 2 * t, h1 = 2 * t + 1;
        half8 u0 = W1f[(h0 * 3 + 0) * 64 + lane];
        half8 u1 = W1f[(h0 * 3 + 1) * 64 + lane];
        half8 u2 = W1f[(h0 * 3 + 2) * 64 + lane];
        half8 v0 = W1f[(h1 * 3 + 0) * 64 + lane];
        half8 v1 = W1f[(h1 * 3 + 1) * 64 + lane];
        half8 v2 = W1f[(h1 * 3 + 2) * 64 + lane];
#pragma unroll
        for (int rn = 0; rn < 2; ++rn) {
            f32x4 a = zz, b = zz;
            a = MFMA16(u0, xf[rn][0], a);
            a = MFMA16(u1, xf[rn][1], a);
            a = MFMA16(u2, xf[rn][2], a);
            b = MFMA16(v0, xf[rn][0], b);
            b = MFMA16(v1, xf[rn][1], b);
            b = MFMA16(v2, xf[rn][2], b);
            hf[t][rn] = pack8(
                fmaxf(a[0], 0.f), fmaxf(a[1], 0.f), fmaxf(a[2], 0.f), fmaxf(a[3], 0.f),
                fmaxf(b[0], 0.f), fmaxf(b[1], 0.f), fmaxf(b[2], 0.f), fmaxf(b[3], 0.f));
        }
    }

    // Layer 2 per om; bias + tanh straight to I.
#pragma unroll
    for (int om = 0; om < 4; ++om) {
        half8 w0 = W2f[(om * 4 + 0) * 64 + lane];
        half8 w1 = W2f[(om * 4 + 1) * 64 + lane];
        half8 w2 = W2f[(om * 4 + 2) * 64 + lane];
        half8 w3 = W2f[(om * 4 + 3) * 64 + lane];
        float b2v[4];
#pragma unroll
        for (int r = 0; r < 4; ++r) b2v[r] = b2[16 * om + 4 * g + r];
#pragma unroll
        for (int rn = 0; rn < 2; ++rn) {
            f32x4 a = zz;
            a = MFMA16(w0, hf[0][rn], a);
            a = MFMA16(w1, hf[1][rn], a);
            a = MFMA16(w2, hf[2][rn], a);
            a = MFMA16(w3, hf[3][rn], a);
#pragma unroll
            for (int r = 0; r < 4; ++r) {
                float y = a[r] + b2v[r];
                float e = __expf(2.f * y);
                I[om][rn][r] = fmaf(-2.f, __builtin_amdgcn_rcpf(e + 1.f), 1.f);
            }
        }
    }
}

// ---------------------------------------------------------------------------
// Self kernel: es[b] = dot(encode(self_obs[b]), Wa_self). 8 waves/block,
// each wave encodes 32 self rows. Weights staged to LDS once per block.
// ---------------------------------------------------------------------------
__global__ void __launch_bounds__(512, 3)
self_kernel(const float* __restrict__ sobs,
            const float* __restrict__ b2,
            char* __restrict__ ws) {
    __shared__ __align__(16) char wlds[WS_WFRAG];
    int tid = threadIdx.x, w = tid >> 6, lane = tid & 63;
    int r0 = (blockIdx.x * 8 + w) * 32;

    stage_weights(ws, wlds, tid);

    float I[4][2][4];
    encode32d(sobs + (size_t)r0 * 83, wlds, b2, lane, I);

    const float* Wasf = (const float*)(ws + WS_WASF);
    float* es = (float*)(ws + WS_ES);

    float was[16];
#pragma unroll
    for (int idx = 0; idx < 16; ++idx) was[idx] = Wasf[lane * 16 + idx];

    float d0 = 0.f, d1 = 0.f;
#pragma unroll
    for (int om = 0; om < 4; ++om)
#pragma unroll
        for (int r = 0; r < 4; ++r) {
            d0 = fmaf(I[om][0][r], was[om * 4 + r], d0);
            d1 = fmaf(I[om][1][r], was[om * 4 + r], d1);
        }
    d0 += __shfl_xor(d0, 16); d0 += __shfl_xor(d0, 32);
    d1 += __shfl_xor(d1, 16); d1 += __shfl_xor(d1, 32);

    if (lane < 16) {
        es[r0 + lane] = d0;
        es[r0 + 16 + lane] = d1;
    }
}

// ---------------------------------------------------------------------------
// Main kernel: one batch item per wave, 8 waves/block, weights in LDS.
// ---------------------------------------------------------------------------
__global__ void __launch_bounds__(512, 3)
main_kernel(const float* __restrict__ nbr,
            const float* __restrict__ edgew,
            const float* __restrict__ b2,
            const float* __restrict__ ba,
            const float* __restrict__ bv,
            const float* __restrict__ bo,
            const char* __restrict__ ws,
            float* __restrict__ out) {
    __shared__ __align__(16) char wlds[WS_WFRAG];
    int tid = threadIdx.x, w = tid >> 6, lane = tid & 63;
    int b = blockIdx.x * 8 + w;
    int g = lane >> 4, m = lane & 15;
    const f32x4 zz = {0.f, 0.f, 0.f, 0.f};

    stage_weights(ws, wlds, tid);

    const float* es = (const float*)(ws + WS_ES);
    float esb = es[b];              // issued early
    float bav = ba[0];
    float ew0 = edgew[b * 32 + m];
    float ew1 = edgew[b * 32 + 16 + m];

    float I[4][2][4];
    encode32d(nbr + (size_t)b * 2656, wlds, b2, lane, I);

    const float* Wafn = (const float*)(ws + WS_WAFN);
    const float* Wopf = (const float*)(ws + WS_WOPF);
    const half8* Wvf  = (const half8*)(wlds + WS_WVF);

    // attention logits: en[row] = dot(I[row], Wa_nbr)
    float wan[16];
#pragma unroll
    for (int idx = 0; idx < 16; ++idx) wan[idx] = Wafn[lane * 16 + idx];

    float en0 = 0.f, en1 = 0.f;
#pragma unroll
    for (int om = 0; om < 4; ++om)
#pragma unroll
        for (int r = 0; r < 4; ++r) {
            en0 = fmaf(I[om][0][r], wan[om * 4 + r], en0);
            en1 = fmaf(I[om][1][r], wan[om * 4 + r], en1);
        }
    en0 += __shfl_xor(en0, 16); en0 += __shfl_xor(en0, 32);
    en1 += __shfl_xor(en1, 16); en1 += __shfl_xor(en1, 32);

    float e0 = esb + en0 + bav; e0 = (e0 > 0.f) ? e0 : 0.2f * e0; e0 *= ew0;
    float e1 = esb + en1 + bav; e1 = (e1 > 0.f) ? e1 : 0.2f * e1; e1 *= ew1;

    // softmax over 32 neighbors; |e| bounded (~7) -> exp fp32-safe w/o max-sub
    float p0 = __expf(e0), p1 = __expf(e1);
    float s = p0 + p1;
#pragma unroll
    for (int msk = 1; msk <= 8; msk <<= 1) s += __shfl_xor(s, msk);
    float inv = __builtin_amdgcn_rcpf(s);
    float a0 = p0 * inv, a1 = p1 * inv;

    // values: V^T = Wv^T @ I^T, B-frag straight from I registers
    half8 vf[2][2];
#pragma unroll
    for (int kt = 0; kt < 2; ++kt)
#pragma unroll
        for (int rn = 0; rn < 2; ++rn)
            vf[kt][rn] = pack8(I[2 * kt][rn][0], I[2 * kt][rn][1],
                               I[2 * kt][rn][2], I[2 * kt][rn][3],
                               I[2 * kt + 1][rn][0], I[2 * kt + 1][rn][1],
                               I[2 * kt + 1][rn][2], I[2 * kt + 1][rn][3]);

    // per-vm scoped acc + immediate alpha-weighted reduce
    float agg[4][4];
#pragma unroll
    for (int vm = 0; vm < 4; ++vm) {
        half8 w0 = Wvf[(vm * 2 + 0) * 64 + lane];
        half8 w1 = Wvf[(vm * 2 + 1) * 64 + lane];
        f32x4 a = zz, b4 = zz;
        a  = MFMA16(w0, vf[0][0], a);
        a  = MFMA16(w1, vf[1][0], a);
        b4 = MFMA16(w0, vf[0][1], b4);
        b4 = MFMA16(w1, vf[1][1], b4);
#pragma unroll
        for (int r = 0; r < 4; ++r) {
            float t = a0 * a[r] + a1 * b4[r];
#pragma unroll
            for (int msk = 1; msk <= 8; msk <<= 1) t += __shfl_xor(t, msk);
            agg[vm][r] = t + bv[16 * vm + 4 * g + r];
        }
    }

    // out[b][j]: lane (g,m) computes j = m over its vo subset, then g-reduce
    float wor[16];
#pragma unroll
    for (int idx = 0; idx < 16; ++idx) wor[idx] = Wopf[lane * 16 + idx];
    float val = 0.f;
#pragma unroll
    for (int vm = 0; vm < 4; ++vm)
#pragma unroll
        for (int r = 0; r < 4; ++r) val = fmaf(agg[vm][r], wor[vm * 4 + r], val);
    val += __shfl_xor(val, 16);
    val += __shfl_xor(val, 32);

    if (lane < 16) out[(size_t)b * 16 + lane] = val + bo[lane];
}

// ---------------------------------------------------------------------------
extern "C" void kernel_launch(void* const* d_in, const int* in_sizes, int n_in,
                              void* d_out, int out_size, void* d_ws, size_t ws_size,
                              hipStream_t stream) {
    const float* self_obs = (const float*)d_in[0];
    const float* nbr      = (const float*)d_in[1];
    const float* ew       = (const float*)d_in[2];
    const float* W1       = (const float*)d_in[3];
    const float* b1       = (const float*)d_in[4];
    const float* W2       = (const float*)d_in[5];
    const float* b2       = (const float*)d_in[6];
    const float* Wa       = (const float*)d_in[7];
    const float* ba       = (const float*)d_in[8];
    const float* Wv       = (const float*)d_in[9];
    const float* bv       = (const float*)d_in[10];
    const float* Wo       = (const float*)d_in[11];
    const float* bo       = (const float*)d_in[12];
    char* ws = (char*)d_ws;
    float* out = (float*)d_out;

    prep_kernel<<<108, 256, 0, stream>>>(W1, b1, W2, Wv, Wa, Wo, ws);
    self_kernel<<<64, 512, 0, stream>>>(self_obs, b2, ws);
    main_kernel<<<2048, 512, 0, stream>>>(nbr, ew, b2, ba, bv, bo, ws, out);
}